// Round 10
// baseline (301.027 us; speedup 1.0000x reference)
//
#include <hip/hip_runtime.h>

#define D 256
typedef unsigned short u16;
typedef __attribute__((ext_vector_type(8))) short bf16x8;
typedef __attribute__((ext_vector_type(4))) float f32x4;

__device__ __forceinline__ float bf2f(u16 u) {
    union { unsigned int i; float f; } x; x.i = ((unsigned int)u) << 16; return x.f;
}
__device__ __forceinline__ u16 f2bf(float f) {
    union { float f; unsigned int i; } x; x.f = f;
    unsigned int r = x.i + 0x7fff + ((x.i >> 16) & 1);   // RNE
    return (u16)(r >> 16);
}
__device__ __forceinline__ unsigned int cvtpk_bf16(float lo, float hi) {
    unsigned int r;
    asm("v_cvt_pk_bf16_f32 %0, %1, %2" : "=v"(r) : "v"(lo), "v"(hi));
    return r;
}
__device__ __forceinline__ void gload16(const void* g, void* l) {
    __builtin_amdgcn_global_load_lds(
        (const __attribute__((address_space(1))) void*)g,
        (__attribute__((address_space(3))) void*)l, 16, 0, 0);
}
// opaque 16B load the compiler cannot serialize
__device__ __forceinline__ bf16x8 gload_row(const u16* p) {
    bf16x8 r;
    asm volatile("global_load_dwordx4 %0, %1, off" : "=&v"(r) : "v"(p));
    return r;
}

// ---------------- setup kernels ----------------

__global__ void init_kernel(int* __restrict__ deg, int n) {
    int i = blockIdx.x * blockDim.x + threadIdx.x;
    if (i < n) deg[i] = 1;   // deg starts at 1 (self-loop)
}

// 1 edge/thread: max wave concurrency to hide atomic latency
__global__ void hist_kernel(const int* __restrict__ dst, int* __restrict__ deg, int e) {
    int i = blockIdx.x * blockDim.x + threadIdx.x;
    if (i < e) atomicAdd(&deg[dst[i]], 1);
}

// ---------------- 3-phase exclusive scan of (deg[i]-1) -> rowptr[0..n] ----------------

__global__ __launch_bounds__(256) void scan_phase1(
    const int* __restrict__ deg, int* __restrict__ bsum,
    float* __restrict__ dinv, int n) {
    __shared__ int red[256];
    int t = threadIdx.x;
    int i0 = blockIdx.x * 1024 + t * 4;
    int s = 0;
    if (i0 + 3 < n) {
        int4 v = *reinterpret_cast<const int4*>(&deg[i0]);
        s = v.x + v.y + v.z + v.w - 4;
        float4 dv;
        dv.x = rsqrtf((float)v.x); dv.y = rsqrtf((float)v.y);
        dv.z = rsqrtf((float)v.z); dv.w = rsqrtf((float)v.w);
        *reinterpret_cast<float4*>(&dinv[i0]) = dv;
    } else {
        for (int j = i0; j < n && j < i0 + 4; ++j) {
            s += deg[j] - 1;
            dinv[j] = rsqrtf((float)deg[j]);
        }
    }
    red[t] = s;
    __syncthreads();
    for (int off = 128; off > 0; off >>= 1) {
        if (t < off) red[t] += red[t + off];
        __syncthreads();
    }
    if (t == 0) bsum[blockIdx.x] = red[0];
}

__global__ __launch_bounds__(256) void scan_phase2(
    const int* __restrict__ bsum, int* __restrict__ boff,
    int* __restrict__ rowptr, int nblk, int n) {
    __shared__ int sums[256];
    int t = threadIdx.x;
    int v = (t < nblk) ? bsum[t] : 0;
    int orig = v;
    sums[t] = v;
    __syncthreads();
    for (int off = 1; off < 256; off <<= 1) {
        int u = (t >= off) ? sums[t - off] : 0;
        __syncthreads();
        sums[t] += u;
        __syncthreads();
    }
    if (t < nblk) boff[t] = sums[t] - orig;
    if (t == nblk - 1) rowptr[n] = sums[t];
}

// writes rowptr AND pre-seeds cursor with the same exclusive prefix,
// so fill's chain is load dst -> atomic -> write (no rowptr lookup).
__global__ __launch_bounds__(256) void scan_phase3(
    const int* __restrict__ deg, const int* __restrict__ boff,
    int* __restrict__ rowptr, int* __restrict__ cursor, int n) {
    __shared__ int sums[256];
    int t = threadIdx.x;
    int i0 = blockIdx.x * 1024 + t * 4;
    int d0 = 0, d1 = 0, d2 = 0, d3 = 0;
    if (i0 + 3 < n) {
        int4 v = *reinterpret_cast<const int4*>(&deg[i0]);
        d0 = v.x - 1; d1 = v.y - 1; d2 = v.z - 1; d3 = v.w - 1;
    } else {
        if (i0 + 0 < n) d0 = deg[i0 + 0] - 1;
        if (i0 + 1 < n) d1 = deg[i0 + 1] - 1;
        if (i0 + 2 < n) d2 = deg[i0 + 2] - 1;
        if (i0 + 3 < n) d3 = deg[i0 + 3] - 1;
    }
    int ts = d0 + d1 + d2 + d3;
    sums[t] = ts;
    __syncthreads();
    for (int off = 1; off < 256; off <<= 1) {
        int u = (t >= off) ? sums[t - off] : 0;
        __syncthreads();
        sums[t] += u;
        __syncthreads();
    }
    int pre = boff[blockIdx.x] + sums[t] - ts;
    if (i0 + 0 < n) { rowptr[i0 + 0] = pre; cursor[i0 + 0] = pre; } pre += d0;
    if (i0 + 1 < n) { rowptr[i0 + 1] = pre; cursor[i0 + 1] = pre; } pre += d1;
    if (i0 + 2 < n) { rowptr[i0 + 2] = pre; cursor[i0 + 2] = pre; } pre += d2;
    if (i0 + 3 < n) { rowptr[i0 + 3] = pre; cursor[i0 + 3] = pre; }
}

// 1 edge/thread, cursor pre-seeded with rowptr
__global__ void fill_kernel(const int* __restrict__ src, const int* __restrict__ dst,
                            int* __restrict__ cursor, int* __restrict__ csr, int e) {
    int i = blockIdx.x * blockDim.x + threadIdx.x;
    if (i < e) {
        int d = dst[i];
        int p = atomicAdd(&cursor[d], 1);
        csr[p] = src[i];
    }
}

// ---------------- conversions ----------------

// W [K=256][N=256] f32 -> Wt [N][K] bf16 (transpose + convert)
__global__ __launch_bounds__(256) void transpose_cvt_kernel(
    const float* __restrict__ W, u16* __restrict__ Wt) {
    __shared__ float t[32][33];
    int bx = blockIdx.x * 32, by = blockIdx.y * 32;
    int tx = threadIdx.x & 31, ty = threadIdx.x >> 5;
#pragma unroll
    for (int i = 0; i < 32; i += 8)
        t[ty + i][tx] = W[(size_t)(bx + ty + i) * D + by + tx];
    __syncthreads();
#pragma unroll
    for (int i = 0; i < 32; i += 8)
        Wt[(size_t)(by + ty + i) * D + bx + tx] = f2bf(t[tx][ty + i]);
}

// ---------------- bf16 MFMA GEMM, tile 64x128 (r9-verbatim) ----------------

// Variant A: A bf16 (gload16 direct-to-LDS). epilogue: *dinv[row].
__global__ __launch_bounds__(256) void mfma_gemm(
    const u16* __restrict__ A, const u16* __restrict__ Bt,
    const float* __restrict__ dinv,
    u16* __restrict__ C, int M)
{
    __shared__ u16 As[64 * 32];
    __shared__ u16 Bs[128 * 32];
    const int tid = threadIdx.x;
    const int lane = tid & 63;
    const int wave = tid >> 6;
    const int wr = wave >> 1, wc = wave & 1;
    const int row0 = blockIdx.y * 64, col0 = blockIdx.x * 128;
    const int l16 = lane & 15, kg = lane >> 4;

    f32x4 acc[2][4] = {};

    for (int k0 = 0; k0 < D; k0 += 32) {
        {
            int r = tid >> 2, c = tid & 3;
            int csw = c ^ ((r >> 1) & 3);
            char* ldsbase_a = (char*)As + ((tid & ~63) << 4);
            int grow = row0 + r; if (grow >= M) grow = M - 1;
            gload16(&A[(size_t)grow * D + k0 + csw * 8], ldsbase_a);
        }
#pragma unroll
        for (int i = 0; i < 2; ++i) {
            int idx = i * 256 + tid;
            int r = idx >> 2, c = idx & 3;
            int csw = c ^ ((r >> 1) & 3);
            char* ldsbase_b = (char*)Bs + ((i * 256 + (tid & ~63)) << 4);
            gload16(&Bt[(size_t)(col0 + r) * D + k0 + csw * 8], ldsbase_b);
        }
        __syncthreads();
        bf16x8 af[2], bfr[4];
        int ksw = kg ^ ((l16 >> 1) & 3);
#pragma unroll
        for (int m = 0; m < 2; ++m)
            af[m] = *reinterpret_cast<const bf16x8*>(&As[(wr * 32 + m * 16 + l16) * 32 + ksw * 8]);
#pragma unroll
        for (int nn = 0; nn < 4; ++nn)
            bfr[nn] = *reinterpret_cast<const bf16x8*>(&Bs[(wc * 64 + nn * 16 + l16) * 32 + ksw * 8]);
#pragma unroll
        for (int m = 0; m < 2; ++m)
#pragma unroll
            for (int nn = 0; nn < 4; ++nn)
                acc[m][nn] = __builtin_amdgcn_mfma_f32_16x16x32_bf16(
                    af[m], bfr[nn], acc[m][nn], 0, 0, 0);
        __syncthreads();
    }

#pragma unroll
    for (int m = 0; m < 2; ++m) {
#pragma unroll
        for (int nn = 0; nn < 4; ++nn) {
            int gcol = col0 + wc * 64 + nn * 16 + l16;
#pragma unroll
            for (int j = 0; j < 4; ++j) {
                int grow = row0 + wr * 32 + m * 16 + kg * 4 + j;
                if (grow >= M) continue;
                C[(size_t)grow * D + gcol] = f2bf(acc[m][nn][j] * dinv[grow]);
            }
        }
    }
}

// Variant B: A f32 (reg-stage + cvt_pk + ds_write). epilogue: relu(+bias).
__global__ __launch_bounds__(256) void mfma_gemm_f32a(
    const float* __restrict__ A, const u16* __restrict__ Bt,
    const float* __restrict__ bias,
    u16* __restrict__ C, int M)
{
    __shared__ u16 As[64 * 32];
    __shared__ u16 Bs[128 * 32];
    const int tid = threadIdx.x;
    const int lane = tid & 63;
    const int wave = tid >> 6;
    const int wr = wave >> 1, wc = wave & 1;
    const int row0 = blockIdx.y * 64, col0 = blockIdx.x * 128;
    const int l16 = lane & 15, kg = lane >> 4;

    f32x4 acc[2][4] = {};

    for (int k0 = 0; k0 < D; k0 += 32) {
#pragma unroll
        for (int i = 0; i < 2; ++i) {
            int idx = i * 256 + tid;
            int r = idx >> 2, c = idx & 3;
            int csw = c ^ ((r >> 1) & 3);
            char* ldsbase_b = (char*)Bs + ((i * 256 + (tid & ~63)) << 4);
            gload16(&Bt[(size_t)(col0 + r) * D + k0 + csw * 8], ldsbase_b);
        }
        {
            int r = tid >> 2, c = tid & 3;
            int csw = c ^ ((r >> 1) & 3);
            int grow = row0 + r; if (grow >= M) grow = M - 1;
            const float* gp = &A[(size_t)grow * D + k0 + csw * 8];
            float4 v0 = *reinterpret_cast<const float4*>(gp);
            float4 v1 = *reinterpret_cast<const float4*>(gp + 4);
            uint4 w;
            w.x = cvtpk_bf16(v0.x, v0.y);
            w.y = cvtpk_bf16(v0.z, v0.w);
            w.z = cvtpk_bf16(v1.x, v1.y);
            w.w = cvtpk_bf16(v1.z, v1.w);
            *reinterpret_cast<uint4*>((char*)As + (tid << 4)) = w;
        }
        __syncthreads();
        bf16x8 af[2], bfr[4];
        int ksw = kg ^ ((l16 >> 1) & 3);
#pragma unroll
        for (int m = 0; m < 2; ++m)
            af[m] = *reinterpret_cast<const bf16x8*>(&As[(wr * 32 + m * 16 + l16) * 32 + ksw * 8]);
#pragma unroll
        for (int nn = 0; nn < 4; ++nn)
            bfr[nn] = *reinterpret_cast<const bf16x8*>(&Bs[(wc * 64 + nn * 16 + l16) * 32 + ksw * 8]);
#pragma unroll
        for (int m = 0; m < 2; ++m)
#pragma unroll
            for (int nn = 0; nn < 4; ++nn)
                acc[m][nn] = __builtin_amdgcn_mfma_f32_16x16x32_bf16(
                    af[m], bfr[nn], acc[m][nn], 0, 0, 0);
        __syncthreads();
    }

#pragma unroll
    for (int m = 0; m < 2; ++m) {
#pragma unroll
        for (int nn = 0; nn < 4; ++nn) {
            int gcol = col0 + wc * 64 + nn * 16 + l16;
#pragma unroll
            for (int j = 0; j < 4; ++j) {
                int grow = row0 + wr * 32 + m * 16 + kg * 4 + j;
                if (grow >= M) continue;
                C[(size_t)grow * D + gcol] = f2bf(fmaxf(acc[m][nn][j] + bias[gcol], 0.f));
            }
        }
    }
}

// ---------------- aggregation (r6/r9-verbatim: full-row, forced-MLP bursts) ----------------
__global__ __launch_bounds__(256) void agg_kernel(
    const u16* __restrict__ hn, const int* __restrict__ rowptr,
    const int* __restrict__ csr, const float* __restrict__ dinv,
    const float* __restrict__ bias,
    u16* __restrict__ out_bf, float* __restrict__ out_f32, int n)
{
    int wave = threadIdx.x >> 6;
    int lane = threadIdx.x & 63;
    int node = blockIdx.x * 4 + wave;
    if (node >= n) return;
    int h = lane >> 5;          // half-wave id: edge parity
    int l5 = lane & 31;
    int c8 = l5 * 8;            // column base (8 bf16 = 16B per lane)

    float a[8] = {0.f, 0.f, 0.f, 0.f, 0.f, 0.f, 0.f, 0.f};

#define ACC8(vv) { \
    a[0] += bf2f((u16)(vv)[0]); a[1] += bf2f((u16)(vv)[1]); \
    a[2] += bf2f((u16)(vv)[2]); a[3] += bf2f((u16)(vv)[3]); \
    a[4] += bf2f((u16)(vv)[4]); a[5] += bf2f((u16)(vv)[5]); \
    a[6] += bf2f((u16)(vv)[6]); a[7] += bf2f((u16)(vv)[7]); }
#define ROWP(s) (&hn[(size_t)(s) * D + c8])

    if (h == 0) {
        bf16x8 v = *reinterpret_cast<const bf16x8*>(ROWP(node));
        ACC8(v);
    }

    int e0 = rowptr[node], e1 = rowptr[node + 1];
    for (int base = e0; base < e1; base += 64) {
        int bi = base + lane;
        int idx = (bi < e1) ? csr[bi] : 0;
        int cnt = e1 - base; if (cnt > 64) cnt = 64;
        int it = 0;
        for (; it + 16 <= cnt; it += 16) {
            int s0 = __shfl(idx, it + 0  + h);
            int s1 = __shfl(idx, it + 2  + h);
            int s2 = __shfl(idx, it + 4  + h);
            int s3 = __shfl(idx, it + 6  + h);
            int s4 = __shfl(idx, it + 8  + h);
            int s5 = __shfl(idx, it + 10 + h);
            int s6 = __shfl(idx, it + 12 + h);
            int s7 = __shfl(idx, it + 14 + h);
            bf16x8 v0 = gload_row(ROWP(s0));
            bf16x8 v1 = gload_row(ROWP(s1));
            bf16x8 v2 = gload_row(ROWP(s2));
            bf16x8 v3 = gload_row(ROWP(s3));
            bf16x8 v4 = gload_row(ROWP(s4));
            bf16x8 v5 = gload_row(ROWP(s5));
            bf16x8 v6 = gload_row(ROWP(s6));
            bf16x8 v7 = gload_row(ROWP(s7));
            asm volatile("s_waitcnt vmcnt(0)" ::: "memory");
            __builtin_amdgcn_sched_barrier(0);
            ACC8(v0); ACC8(v1); ACC8(v2); ACC8(v3);
            ACC8(v4); ACC8(v5); ACC8(v6); ACC8(v7);
        }
        for (; it + 8 <= cnt; it += 8) {
            int s0 = __shfl(idx, it + 0 + h);
            int s1 = __shfl(idx, it + 2 + h);
            int s2 = __shfl(idx, it + 4 + h);
            int s3 = __shfl(idx, it + 6 + h);
            bf16x8 v0 = gload_row(ROWP(s0));
            bf16x8 v1 = gload_row(ROWP(s1));
            bf16x8 v2 = gload_row(ROWP(s2));
            bf16x8 v3 = gload_row(ROWP(s3));
            asm volatile("s_waitcnt vmcnt(0)" ::: "memory");
            __builtin_amdgcn_sched_barrier(0);
            ACC8(v0); ACC8(v1); ACC8(v2); ACC8(v3);
        }
        for (; it + 2 <= cnt; it += 2) {
            int s0 = __shfl(idx, it + h);
            bf16x8 v0 = *reinterpret_cast<const bf16x8*>(ROWP(s0));
            ACC8(v0);
        }
        if (it < cnt) {
            int s0 = __shfl(idx, it);
            if (h == 0) {
                bf16x8 v0 = *reinterpret_cast<const bf16x8*>(ROWP(s0));
                ACC8(v0);
            }
        }
    }
#undef ACC8
#undef ROWP

#pragma unroll
    for (int j = 0; j < 8; ++j) a[j] += __shfl(a[j], lane ^ 32);

    if (h == 0) {
        float di = dinv[node];
#pragma unroll
        for (int j = 0; j < 8; ++j) a[j] = fmaxf(a[j] * di + bias[c8 + j], 0.f);
        if (out_bf) {
            bf16x8 o;
#pragma unroll
            for (int j = 0; j < 8; ++j) o[j] = (short)f2bf(a[j]);
            *reinterpret_cast<bf16x8*>(&out_bf[(size_t)node * D + c8]) = o;
        } else {
            float4 o0, o1;
            o0.x = a[0]; o0.y = a[1]; o0.z = a[2]; o0.w = a[3];
            o1.x = a[4]; o1.y = a[5]; o1.z = a[6]; o1.w = a[7];
            *reinterpret_cast<float4*>(&out_f32[(size_t)node * D + c8 + 0]) = o0;
            *reinterpret_cast<float4*>(&out_f32[(size_t)node * D + c8 + 4]) = o1;
        }
    }
}

// ---------------- launch ----------------

extern "C" void kernel_launch(void* const* d_in, const int* in_sizes, int n_in,
                              void* d_out, int out_size, void* d_ws, size_t ws_size,
                              hipStream_t stream) {
    const float* input  = (const float*)d_in[0];
    const int*   edge   = (const int*)d_in[1];
    const float* weight = (const float*)d_in[2];
    const float* bias   = (const float*)d_in[3];
    const float* conv_w = (const float*)d_in[4];
    const float* conv_b = (const float*)d_in[5];
    float* out = (float*)d_out;

    const int n = in_sizes[0] / D;     // 50000
    const int E = in_sizes[1] / 2;     // 800000
    const int* src = edge;
    const int* dst = edge + E;

    char* ws = (char*)d_ws;
    size_t off = 0;
    auto alloc = [&](size_t bytes) -> void* {
        void* p = ws + off;
        off = (off + bytes + 255) & ~(size_t)255;
        return p;
    };
    u16*   bufA   = (u16*)alloc((size_t)n * D * sizeof(u16));   // x1 / x2
    u16*   bufB   = (u16*)alloc((size_t)n * D * sizeof(u16));   // hn / hn2
    u16*   Wt     = (u16*)alloc((size_t)3 * D * D * sizeof(u16));
    int*   deg    = (int*)alloc((size_t)n * sizeof(int));
    int*   cursor = (int*)alloc((size_t)n * sizeof(int));
    float* dinv   = (float*)alloc((size_t)n * sizeof(float));
    int*   rowptr = (int*)alloc((size_t)(n + 1) * sizeof(int));
    int*   csr    = (int*)alloc((size_t)E * sizeof(int));
    int    nscan  = (n + 1023) / 1024;
    int*   bsum   = (int*)alloc((size_t)nscan * sizeof(int));
    int*   boff   = (int*)alloc((size_t)nscan * sizeof(int));

    int nb = (n + 255) / 256;
    int eb1 = (E + 255) / 256;           // 1 edge/thread grids
    init_kernel<<<nb, 256, 0, stream>>>(deg, n);
    hist_kernel<<<eb1, 256, 0, stream>>>(dst, deg, E);
    scan_phase1<<<nscan, 256, 0, stream>>>(deg, bsum, dinv, n);
    scan_phase2<<<1, 256, 0, stream>>>(bsum, boff, rowptr, nscan, n);
    scan_phase3<<<nscan, 256, 0, stream>>>(deg, boff, rowptr, cursor, n);
    fill_kernel<<<eb1, 256, 0, stream>>>(src, dst, cursor, csr, E);

    dim3 tgrid(8, 8);
    transpose_cvt_kernel<<<tgrid, 256, 0, stream>>>(weight, Wt);
    transpose_cvt_kernel<<<tgrid, 256, 0, stream>>>(conv_w, Wt + D * D);
    transpose_cvt_kernel<<<tgrid, 256, 0, stream>>>(conv_w + D * D, Wt + 2 * D * D);

    dim3 ggrid(D / 128, (n + 63) / 64);   // 2 x 782 = 1564 blocks
    dim3 agrid((n + 3) / 4);

    // x1 = relu(input @ W + b)          -> bufA (bf16, fuses f32->bf16 cvt)
    mfma_gemm_f32a<<<ggrid, 256, 0, stream>>>(input, Wt, bias, bufA, n);
    // hn = (x1 @ W0) * dinv[row]        -> bufB
    mfma_gemm<<<ggrid, 256, 0, stream>>>(bufA, Wt + D * D, dinv, bufB, n);
    // x2 = relu(dinv * agg(hn) + b0)    -> bufA
    agg_kernel<<<agrid, 256, 0, stream>>>(bufB, rowptr, csr, dinv, conv_b, bufA, nullptr, n);
    // hn2 = (x2 @ W1) * dinv[row]       -> bufB
    mfma_gemm<<<ggrid, 256, 0, stream>>>(bufA, Wt + 2 * D * D, dinv, bufB, n);
    // out = relu(dinv * agg(hn2) + b1)  -> out (f32)
    agg_kernel<<<agrid, 256, 0, stream>>>(bufB, rowptr, csr, dinv, conv_b + D, nullptr, out, n);
}

// Round 11
// 294.806 us; speedup vs baseline: 1.0211x; 1.0211x over previous
//
#include <hip/hip_runtime.h>

#define D 256
typedef unsigned short u16;
typedef __attribute__((ext_vector_type(8))) short bf16x8;
typedef __attribute__((ext_vector_type(4))) float f32x4;

__device__ __forceinline__ float bf2f(u16 u) {
    union { unsigned int i; float f; } x; x.i = ((unsigned int)u) << 16; return x.f;
}
__device__ __forceinline__ u16 f2bf(float f) {
    union { float f; unsigned int i; } x; x.f = f;
    unsigned int r = x.i + 0x7fff + ((x.i >> 16) & 1);   // RNE
    return (u16)(r >> 16);
}
__device__ __forceinline__ unsigned int cvtpk_bf16(float lo, float hi) {
    unsigned int r;
    asm("v_cvt_pk_bf16_f32 %0, %1, %2" : "=v"(r) : "v"(lo), "v"(hi));
    return r;
}
__device__ __forceinline__ void gload16(const void* g, void* l) {
    __builtin_amdgcn_global_load_lds(
        (const __attribute__((address_space(1))) void*)g,
        (__attribute__((address_space(3))) void*)l, 16, 0, 0);
}
// opaque 16B load the compiler cannot serialize
__device__ __forceinline__ bf16x8 gload_row(const u16* p) {
    bf16x8 r;
    asm volatile("global_load_dwordx4 %0, %1, off" : "=&v"(r) : "v"(p));
    return r;
}

// ---------------- fused: init (deg=1) || transpose_cvt x3 ----------------
// blocks [0, nb): deg init; blocks [nb, nb+192): transpose (w = t/64, 8x8 tiles)
__global__ __launch_bounds__(256) void fused_init_tr(
    int* __restrict__ deg, int n, int nb,
    const float* __restrict__ W0, const float* __restrict__ CW,
    u16* __restrict__ Wt)
{
    int bid = blockIdx.x;
    if (bid < nb) {
        int i = bid * 256 + threadIdx.x;
        if (i < n) deg[i] = 1;   // deg starts at 1 (self-loop)
    } else {
        __shared__ float t[32][33];
        int tt = bid - nb;
        int w = tt >> 6, r = tt & 63;
        const float* W = (w == 0) ? W0 : (CW + (size_t)(w - 1) * D * D);
        u16* Wo = Wt + (size_t)w * D * D;
        int bx = (r & 7) * 32, by = (r >> 3) * 32;
        int tx = threadIdx.x & 31, ty = threadIdx.x >> 5;
#pragma unroll
        for (int i = 0; i < 32; i += 8)
            t[ty + i][tx] = W[(size_t)(bx + ty + i) * D + by + tx];
        __syncthreads();
#pragma unroll
        for (int i = 0; i < 32; i += 8)
            Wo[(size_t)(by + ty + i) * D + bx + tx] = f2bf(t[tx][ty + i]);
    }
}

// ---------------- 3-phase exclusive scan of (deg[i]-1) -> rowptr[0..n] ----------------

__global__ __launch_bounds__(256) void scan_phase1(
    const int* __restrict__ deg, int* __restrict__ bsum,
    float* __restrict__ dinv, int n) {
    __shared__ int red[256];
    int t = threadIdx.x;
    int i0 = blockIdx.x * 1024 + t * 4;
    int s = 0;
    if (i0 + 3 < n) {
        int4 v = *reinterpret_cast<const int4*>(&deg[i0]);
        s = v.x + v.y + v.z + v.w - 4;
        float4 dv;
        dv.x = rsqrtf((float)v.x); dv.y = rsqrtf((float)v.y);
        dv.z = rsqrtf((float)v.z); dv.w = rsqrtf((float)v.w);
        *reinterpret_cast<float4*>(&dinv[i0]) = dv;
    } else {
        for (int j = i0; j < n && j < i0 + 4; ++j) {
            s += deg[j] - 1;
            dinv[j] = rsqrtf((float)deg[j]);
        }
    }
    red[t] = s;
    __syncthreads();
    for (int off = 128; off > 0; off >>= 1) {
        if (t < off) red[t] += red[t + off];
        __syncthreads();
    }
    if (t == 0) bsum[blockIdx.x] = red[0];
}

__global__ __launch_bounds__(256) void scan_phase2(
    const int* __restrict__ bsum, int* __restrict__ boff,
    int* __restrict__ rowptr, int nblk, int n) {
    __shared__ int sums[256];
    int t = threadIdx.x;
    int v = (t < nblk) ? bsum[t] : 0;
    int orig = v;
    sums[t] = v;
    __syncthreads();
    for (int off = 1; off < 256; off <<= 1) {
        int u = (t >= off) ? sums[t - off] : 0;
        __syncthreads();
        sums[t] += u;
        __syncthreads();
    }
    if (t < nblk) boff[t] = sums[t] - orig;
    if (t == nblk - 1) rowptr[n] = sums[t];
}

__global__ __launch_bounds__(256) void scan_phase3(
    const int* __restrict__ deg, const int* __restrict__ boff,
    int* __restrict__ rowptr, int* __restrict__ cursor, int n) {
    __shared__ int sums[256];
    int t = threadIdx.x;
    int i0 = blockIdx.x * 1024 + t * 4;
    int d0 = 0, d1 = 0, d2 = 0, d3 = 0;
    if (i0 + 3 < n) {
        int4 v = *reinterpret_cast<const int4*>(&deg[i0]);
        d0 = v.x - 1; d1 = v.y - 1; d2 = v.z - 1; d3 = v.w - 1;
    } else {
        if (i0 + 0 < n) d0 = deg[i0 + 0] - 1;
        if (i0 + 1 < n) d1 = deg[i0 + 1] - 1;
        if (i0 + 2 < n) d2 = deg[i0 + 2] - 1;
        if (i0 + 3 < n) d3 = deg[i0 + 3] - 1;
    }
    int ts = d0 + d1 + d2 + d3;
    sums[t] = ts;
    __syncthreads();
    for (int off = 1; off < 256; off <<= 1) {
        int u = (t >= off) ? sums[t - off] : 0;
        __syncthreads();
        sums[t] += u;
        __syncthreads();
    }
    int pre = boff[blockIdx.x] + sums[t] - ts;
    if (i0 + 0 < n) { rowptr[i0 + 0] = pre; cursor[i0 + 0] = pre; } pre += d0;
    if (i0 + 1 < n) { rowptr[i0 + 1] = pre; cursor[i0 + 1] = pre; } pre += d1;
    if (i0 + 2 < n) { rowptr[i0 + 2] = pre; cursor[i0 + 2] = pre; } pre += d2;
    if (i0 + 3 < n) { rowptr[i0 + 3] = pre; cursor[i0 + 3] = pre; }
}

// ---------------- fused: GEMM1 (f32 A, relu+bias) || hist ----------------
// blocks [0, ng): gemm tile (col0=(bid&1)*128, row0=(bid>>1)*64); rest: hist 1 edge/thread
__global__ __launch_bounds__(256) void fused_gemm1_hist(
    const float* __restrict__ A, const u16* __restrict__ Bt,
    const float* __restrict__ bias, u16* __restrict__ C, int M, int ng,
    const int* __restrict__ dst, int* __restrict__ deg, int E)
{
    int bid = blockIdx.x;
    if (bid >= ng) {
        int i = (bid - ng) * 256 + threadIdx.x;
        if (i < E) atomicAdd(&deg[dst[i]], 1);
        return;
    }
    __shared__ u16 As[64 * 32];
    __shared__ u16 Bs[128 * 32];
    const int tid = threadIdx.x;
    const int lane = tid & 63;
    const int wave = tid >> 6;
    const int wr = wave >> 1, wc = wave & 1;
    const int row0 = (bid >> 1) * 64, col0 = (bid & 1) * 128;
    const int l16 = lane & 15, kg = lane >> 4;

    f32x4 acc[2][4] = {};

    for (int k0 = 0; k0 < D; k0 += 32) {
#pragma unroll
        for (int i = 0; i < 2; ++i) {
            int idx = i * 256 + tid;
            int r = idx >> 2, c = idx & 3;
            int csw = c ^ ((r >> 1) & 3);
            char* ldsbase_b = (char*)Bs + ((i * 256 + (tid & ~63)) << 4);
            gload16(&Bt[(size_t)(col0 + r) * D + k0 + csw * 8], ldsbase_b);
        }
        {
            int r = tid >> 2, c = tid & 3;
            int csw = c ^ ((r >> 1) & 3);
            int grow = row0 + r; if (grow >= M) grow = M - 1;
            const float* gp = &A[(size_t)grow * D + k0 + csw * 8];
            float4 v0 = *reinterpret_cast<const float4*>(gp);
            float4 v1 = *reinterpret_cast<const float4*>(gp + 4);
            uint4 w;
            w.x = cvtpk_bf16(v0.x, v0.y);
            w.y = cvtpk_bf16(v0.z, v0.w);
            w.z = cvtpk_bf16(v1.x, v1.y);
            w.w = cvtpk_bf16(v1.z, v1.w);
            *reinterpret_cast<uint4*>((char*)As + (tid << 4)) = w;
        }
        __syncthreads();
        bf16x8 af[2], bfr[4];
        int ksw = kg ^ ((l16 >> 1) & 3);
#pragma unroll
        for (int m = 0; m < 2; ++m)
            af[m] = *reinterpret_cast<const bf16x8*>(&As[(wr * 32 + m * 16 + l16) * 32 + ksw * 8]);
#pragma unroll
        for (int nn = 0; nn < 4; ++nn)
            bfr[nn] = *reinterpret_cast<const bf16x8*>(&Bs[(wc * 64 + nn * 16 + l16) * 32 + ksw * 8]);
#pragma unroll
        for (int m = 0; m < 2; ++m)
#pragma unroll
            for (int nn = 0; nn < 4; ++nn)
                acc[m][nn] = __builtin_amdgcn_mfma_f32_16x16x32_bf16(
                    af[m], bfr[nn], acc[m][nn], 0, 0, 0);
        __syncthreads();
    }

#pragma unroll
    for (int m = 0; m < 2; ++m) {
#pragma unroll
        for (int nn = 0; nn < 4; ++nn) {
            int gcol = col0 + wc * 64 + nn * 16 + l16;
#pragma unroll
            for (int j = 0; j < 4; ++j) {
                int grow = row0 + wr * 32 + m * 16 + kg * 4 + j;
                if (grow >= M) continue;
                C[(size_t)grow * D + gcol] = f2bf(fmaxf(acc[m][nn][j] + bias[gcol], 0.f));
            }
        }
    }
}

// ---------------- fused: GEMM2 (bf16 A, *dinv) || fill ----------------
__global__ __launch_bounds__(256) void fused_gemm2_fill(
    const u16* __restrict__ A, const u16* __restrict__ Bt,
    const float* __restrict__ dinv, u16* __restrict__ C, int M, int ng,
    const int* __restrict__ src, const int* __restrict__ dst,
    int* __restrict__ cursor, int* __restrict__ csr, int E)
{
    int bid = blockIdx.x;
    if (bid >= ng) {
        int i = (bid - ng) * 256 + threadIdx.x;
        if (i < E) {
            int d = dst[i];
            int p = atomicAdd(&cursor[d], 1);
            csr[p] = src[i];
        }
        return;
    }
    __shared__ u16 As[64 * 32];
    __shared__ u16 Bs[128 * 32];
    const int tid = threadIdx.x;
    const int lane = tid & 63;
    const int wave = tid >> 6;
    const int wr = wave >> 1, wc = wave & 1;
    const int row0 = (bid >> 1) * 64, col0 = (bid & 1) * 128;
    const int l16 = lane & 15, kg = lane >> 4;

    f32x4 acc[2][4] = {};

    for (int k0 = 0; k0 < D; k0 += 32) {
        {
            int r = tid >> 2, c = tid & 3;
            int csw = c ^ ((r >> 1) & 3);
            char* ldsbase_a = (char*)As + ((tid & ~63) << 4);
            int grow = row0 + r; if (grow >= M) grow = M - 1;
            gload16(&A[(size_t)grow * D + k0 + csw * 8], ldsbase_a);
        }
#pragma unroll
        for (int i = 0; i < 2; ++i) {
            int idx = i * 256 + tid;
            int r = idx >> 2, c = idx & 3;
            int csw = c ^ ((r >> 1) & 3);
            char* ldsbase_b = (char*)Bs + ((i * 256 + (tid & ~63)) << 4);
            gload16(&Bt[(size_t)(col0 + r) * D + k0 + csw * 8], ldsbase_b);
        }
        __syncthreads();
        bf16x8 af[2], bfr[4];
        int ksw = kg ^ ((l16 >> 1) & 3);
#pragma unroll
        for (int m = 0; m < 2; ++m)
            af[m] = *reinterpret_cast<const bf16x8*>(&As[(wr * 32 + m * 16 + l16) * 32 + ksw * 8]);
#pragma unroll
        for (int nn = 0; nn < 4; ++nn)
            bfr[nn] = *reinterpret_cast<const bf16x8*>(&Bs[(wc * 64 + nn * 16 + l16) * 32 + ksw * 8]);
#pragma unroll
        for (int m = 0; m < 2; ++m)
#pragma unroll
            for (int nn = 0; nn < 4; ++nn)
                acc[m][nn] = __builtin_amdgcn_mfma_f32_16x16x32_bf16(
                    af[m], bfr[nn], acc[m][nn], 0, 0, 0);
        __syncthreads();
    }

#pragma unroll
    for (int m = 0; m < 2; ++m) {
#pragma unroll
        for (int nn = 0; nn < 4; ++nn) {
            int gcol = col0 + wc * 64 + nn * 16 + l16;
#pragma unroll
            for (int j = 0; j < 4; ++j) {
                int grow = row0 + wr * 32 + m * 16 + kg * 4 + j;
                if (grow >= M) continue;
                C[(size_t)grow * D + gcol] = f2bf(acc[m][nn][j] * dinv[grow]);
            }
        }
    }
}

// ---------------- standalone GEMM (bf16 A, *dinv) for layer 2 ----------------
__global__ __launch_bounds__(256) void mfma_gemm(
    const u16* __restrict__ A, const u16* __restrict__ Bt,
    const float* __restrict__ dinv,
    u16* __restrict__ C, int M)
{
    __shared__ u16 As[64 * 32];
    __shared__ u16 Bs[128 * 32];
    const int tid = threadIdx.x;
    const int lane = tid & 63;
    const int wave = tid >> 6;
    const int wr = wave >> 1, wc = wave & 1;
    const int row0 = blockIdx.y * 64, col0 = blockIdx.x * 128;
    const int l16 = lane & 15, kg = lane >> 4;

    f32x4 acc[2][4] = {};

    for (int k0 = 0; k0 < D; k0 += 32) {
        {
            int r = tid >> 2, c = tid & 3;
            int csw = c ^ ((r >> 1) & 3);
            char* ldsbase_a = (char*)As + ((tid & ~63) << 4);
            int grow = row0 + r; if (grow >= M) grow = M - 1;
            gload16(&A[(size_t)grow * D + k0 + csw * 8], ldsbase_a);
        }
#pragma unroll
        for (int i = 0; i < 2; ++i) {
            int idx = i * 256 + tid;
            int r = idx >> 2, c = idx & 3;
            int csw = c ^ ((r >> 1) & 3);
            char* ldsbase_b = (char*)Bs + ((i * 256 + (tid & ~63)) << 4);
            gload16(&Bt[(size_t)(col0 + r) * D + k0 + csw * 8], ldsbase_b);
        }
        __syncthreads();
        bf16x8 af[2], bfr[4];
        int ksw = kg ^ ((l16 >> 1) & 3);
#pragma unroll
        for (int m = 0; m < 2; ++m)
            af[m] = *reinterpret_cast<const bf16x8*>(&As[(wr * 32 + m * 16 + l16) * 32 + ksw * 8]);
#pragma unroll
        for (int nn = 0; nn < 4; ++nn)
            bfr[nn] = *reinterpret_cast<const bf16x8*>(&Bs[(wc * 64 + nn * 16 + l16) * 32 + ksw * 8]);
#pragma unroll
        for (int m = 0; m < 2; ++m)
#pragma unroll
            for (int nn = 0; nn < 4; ++nn)
                acc[m][nn] = __builtin_amdgcn_mfma_f32_16x16x32_bf16(
                    af[m], bfr[nn], acc[m][nn], 0, 0, 0);
        __syncthreads();
    }

#pragma unroll
    for (int m = 0; m < 2; ++m) {
#pragma unroll
        for (int nn = 0; nn < 4; ++nn) {
            int gcol = col0 + wc * 64 + nn * 16 + l16;
#pragma unroll
            for (int j = 0; j < 4; ++j) {
                int grow = row0 + wr * 32 + m * 16 + kg * 4 + j;
                if (grow >= M) continue;
                C[(size_t)grow * D + gcol] = f2bf(acc[m][nn][j] * dinv[grow]);
            }
        }
    }
}

// ---------------- aggregation (r6/r9-verbatim: full-row, forced-MLP bursts) ----------------
__global__ __launch_bounds__(256) void agg_kernel(
    const u16* __restrict__ hn, const int* __restrict__ rowptr,
    const int* __restrict__ csr, const float* __restrict__ dinv,
    const float* __restrict__ bias,
    u16* __restrict__ out_bf, float* __restrict__ out_f32, int n)
{
    int wave = threadIdx.x >> 6;
    int lane = threadIdx.x & 63;
    int node = blockIdx.x * 4 + wave;
    if (node >= n) return;
    int h = lane >> 5;          // half-wave id: edge parity
    int l5 = lane & 31;
    int c8 = l5 * 8;            // column base (8 bf16 = 16B per lane)

    float a[8] = {0.f, 0.f, 0.f, 0.f, 0.f, 0.f, 0.f, 0.f};

#define ACC8(vv) { \
    a[0] += bf2f((u16)(vv)[0]); a[1] += bf2f((u16)(vv)[1]); \
    a[2] += bf2f((u16)(vv)[2]); a[3] += bf2f((u16)(vv)[3]); \
    a[4] += bf2f((u16)(vv)[4]); a[5] += bf2f((u16)(vv)[5]); \
    a[6] += bf2f((u16)(vv)[6]); a[7] += bf2f((u16)(vv)[7]); }
#define ROWP(s) (&hn[(size_t)(s) * D + c8])

    if (h == 0) {
        bf16x8 v = *reinterpret_cast<const bf16x8*>(ROWP(node));
        ACC8(v);
    }

    int e0 = rowptr[node], e1 = rowptr[node + 1];
    for (int base = e0; base < e1; base += 64) {
        int bi = base + lane;
        int idx = (bi < e1) ? csr[bi] : 0;
        int cnt = e1 - base; if (cnt > 64) cnt = 64;
        int it = 0;
        for (; it + 16 <= cnt; it += 16) {
            int s0 = __shfl(idx, it + 0  + h);
            int s1 = __shfl(idx, it + 2  + h);
            int s2 = __shfl(idx, it + 4  + h);
            int s3 = __shfl(idx, it + 6  + h);
            int s4 = __shfl(idx, it + 8  + h);
            int s5 = __shfl(idx, it + 10 + h);
            int s6 = __shfl(idx, it + 12 + h);
            int s7 = __shfl(idx, it + 14 + h);
            bf16x8 v0 = gload_row(ROWP(s0));
            bf16x8 v1 = gload_row(ROWP(s1));
            bf16x8 v2 = gload_row(ROWP(s2));
            bf16x8 v3 = gload_row(ROWP(s3));
            bf16x8 v4 = gload_row(ROWP(s4));
            bf16x8 v5 = gload_row(ROWP(s5));
            bf16x8 v6 = gload_row(ROWP(s6));
            bf16x8 v7 = gload_row(ROWP(s7));
            asm volatile("s_waitcnt vmcnt(0)" ::: "memory");
            __builtin_amdgcn_sched_barrier(0);
            ACC8(v0); ACC8(v1); ACC8(v2); ACC8(v3);
            ACC8(v4); ACC8(v5); ACC8(v6); ACC8(v7);
        }
        for (; it + 8 <= cnt; it += 8) {
            int s0 = __shfl(idx, it + 0 + h);
            int s1 = __shfl(idx, it + 2 + h);
            int s2 = __shfl(idx, it + 4 + h);
            int s3 = __shfl(idx, it + 6 + h);
            bf16x8 v0 = gload_row(ROWP(s0));
            bf16x8 v1 = gload_row(ROWP(s1));
            bf16x8 v2 = gload_row(ROWP(s2));
            bf16x8 v3 = gload_row(ROWP(s3));
            asm volatile("s_waitcnt vmcnt(0)" ::: "memory");
            __builtin_amdgcn_sched_barrier(0);
            ACC8(v0); ACC8(v1); ACC8(v2); ACC8(v3);
        }
        for (; it + 2 <= cnt; it += 2) {
            int s0 = __shfl(idx, it + h);
            bf16x8 v0 = *reinterpret_cast<const bf16x8*>(ROWP(s0));
            ACC8(v0);
        }
        if (it < cnt) {
            int s0 = __shfl(idx, it);
            if (h == 0) {
                bf16x8 v0 = *reinterpret_cast<const bf16x8*>(ROWP(s0));
                ACC8(v0);
            }
        }
    }
#undef ACC8
#undef ROWP

#pragma unroll
    for (int j = 0; j < 8; ++j) a[j] += __shfl(a[j], lane ^ 32);

    if (h == 0) {
        float di = dinv[node];
#pragma unroll
        for (int j = 0; j < 8; ++j) a[j] = fmaxf(a[j] * di + bias[c8 + j], 0.f);
        if (out_bf) {
            bf16x8 o;
#pragma unroll
            for (int j = 0; j < 8; ++j) o[j] = (short)f2bf(a[j]);
            *reinterpret_cast<bf16x8*>(&out_bf[(size_t)node * D + c8]) = o;
        } else {
            float4 o0, o1;
            o0.x = a[0]; o0.y = a[1]; o0.z = a[2]; o0.w = a[3];
            o1.x = a[4]; o1.y = a[5]; o1.z = a[6]; o1.w = a[7];
            *reinterpret_cast<float4*>(&out_f32[(size_t)node * D + c8 + 0]) = o0;
            *reinterpret_cast<float4*>(&out_f32[(size_t)node * D + c8 + 4]) = o1;
        }
    }
}

// ---------------- launch ----------------

extern "C" void kernel_launch(void* const* d_in, const int* in_sizes, int n_in,
                              void* d_out, int out_size, void* d_ws, size_t ws_size,
                              hipStream_t stream) {
    const float* input  = (const float*)d_in[0];
    const int*   edge   = (const int*)d_in[1];
    const float* weight = (const float*)d_in[2];
    const float* bias   = (const float*)d_in[3];
    const float* conv_w = (const float*)d_in[4];
    const float* conv_b = (const float*)d_in[5];
    float* out = (float*)d_out;

    const int n = in_sizes[0] / D;     // 50000
    const int E = in_sizes[1] / 2;     // 800000
    const int* src = edge;
    const int* dst = edge + E;

    char* ws = (char*)d_ws;
    size_t off = 0;
    auto alloc = [&](size_t bytes) -> void* {
        void* p = ws + off;
        off = (off + bytes + 255) & ~(size_t)255;
        return p;
    };
    u16*   bufA   = (u16*)alloc((size_t)n * D * sizeof(u16));   // x1 / x2
    u16*   bufB   = (u16*)alloc((size_t)n * D * sizeof(u16));   // hn / hn2
    u16*   Wt     = (u16*)alloc((size_t)3 * D * D * sizeof(u16));
    int*   deg    = (int*)alloc((size_t)n * sizeof(int));
    int*   cursor = (int*)alloc((size_t)n * sizeof(int));
    float* dinv   = (float*)alloc((size_t)n * sizeof(float));
    int*   rowptr = (int*)alloc((size_t)(n + 1) * sizeof(int));
    int*   csr    = (int*)alloc((size_t)E * sizeof(int));
    int    nscan  = (n + 1023) / 1024;
    int*   bsum   = (int*)alloc((size_t)nscan * sizeof(int));
    int*   boff   = (int*)alloc((size_t)nscan * sizeof(int));

    int nb  = (n + 255) / 256;           // init blocks (196)
    int eb1 = (E + 255) / 256;           // 1 edge/thread blocks (3125)
    int ng  = 2 * ((n + 63) / 64);       // gemm blocks (1564)

    // init || transpose x3
    fused_init_tr<<<nb + 192, 256, 0, stream>>>(deg, n, nb, weight, conv_w, Wt);
    // GEMM1 (x1 = relu(input@W + b) -> bufA) || hist
    fused_gemm1_hist<<<ng + eb1, 256, 0, stream>>>(input, Wt, bias, bufA, n, ng, dst, deg, E);
    // scan chain (rowptr, cursor pre-seed, dinv)
    scan_phase1<<<nscan, 256, 0, stream>>>(deg, bsum, dinv, n);
    scan_phase2<<<1, 256, 0, stream>>>(bsum, boff, rowptr, nscan, n);
    scan_phase3<<<nscan, 256, 0, stream>>>(deg, boff, rowptr, cursor, n);
    // GEMM2 (hn = (x1@W0)*dinv -> bufB) || fill (csr)
    fused_gemm2_fill<<<ng + eb1, 256, 0, stream>>>(bufA, Wt + D * D, dinv, bufB, n, ng,
                                                   src, dst, cursor, csr, E);

    dim3 ggrid(D / 128, (n + 63) / 64);
    dim3 agrid((n + 3) / 4);
    // x2 = relu(dinv * agg(hn) + b0)    -> bufA
    agg_kernel<<<agrid, 256, 0, stream>>>(bufB, rowptr, csr, dinv, conv_b, bufA, nullptr, n);
    // hn2 = (x2 @ W1) * dinv[row]       -> bufB
    mfma_gemm<<<ggrid, 256, 0, stream>>>(bufA, Wt + 2 * D * D, dinv, bufB, n);
    // out = relu(dinv * agg(hn2) + b1)  -> out (f32)
    agg_kernel<<<agrid, 256, 0, stream>>>(bufB, rowptr, csr, dinv, conv_b + D, nullptr, out, n);
}

// Round 12
// 286.997 us; speedup vs baseline: 1.0489x; 1.0272x over previous
//
#include <hip/hip_runtime.h>

#define D 256
typedef unsigned short u16;
typedef __attribute__((ext_vector_type(8))) short bf16x8;
typedef __attribute__((ext_vector_type(4))) float f32x4;

__device__ __forceinline__ float bf2f(u16 u) {
    union { unsigned int i; float f; } x; x.i = ((unsigned int)u) << 16; return x.f;
}
__device__ __forceinline__ u16 f2bf(float f) {
    union { float f; unsigned int i; } x; x.f = f;
    unsigned int r = x.i + 0x7fff + ((x.i >> 16) & 1);   // RNE
    return (u16)(r >> 16);
}
__device__ __forceinline__ unsigned int cvtpk_bf16(float lo, float hi) {
    unsigned int r;
    asm("v_cvt_pk_bf16_f32 %0, %1, %2" : "=v"(r) : "v"(lo), "v"(hi));
    return r;
}
__device__ __forceinline__ void gload16(const void* g, void* l) {
    __builtin_amdgcn_global_load_lds(
        (const __attribute__((address_space(1))) void*)g,
        (__attribute__((address_space(3))) void*)l, 16, 0, 0);
}
// opaque 16B load the compiler cannot serialize
__device__ __forceinline__ bf16x8 gload_row(const u16* p) {
    bf16x8 r;
    asm volatile("global_load_dwordx4 %0, %1, off" : "=&v"(r) : "v"(p));
    return r;
}

// ---------------- fused: init (deg=1) || transpose_cvt x3 ----------------
__global__ __launch_bounds__(256) void fused_init_tr(
    int* __restrict__ deg, int n, int nb,
    const float* __restrict__ W0, const float* __restrict__ CW,
    u16* __restrict__ Wt)
{
    int bid = blockIdx.x;
    if (bid < nb) {
        int i = bid * 256 + threadIdx.x;
        if (i < n) deg[i] = 1;   // deg starts at 1 (self-loop)
    } else {
        __shared__ float t[32][33];
        int tt = bid - nb;
        int w = tt >> 6, r = tt & 63;
        const float* W = (w == 0) ? W0 : (CW + (size_t)(w - 1) * D * D);
        u16* Wo = Wt + (size_t)w * D * D;
        int bx = (r & 7) * 32, by = (r >> 3) * 32;
        int tx = threadIdx.x & 31, ty = threadIdx.x >> 5;
#pragma unroll
        for (int i = 0; i < 32; i += 8)
            t[ty + i][tx] = W[(size_t)(bx + ty + i) * D + by + tx];
        __syncthreads();
#pragma unroll
        for (int i = 0; i < 32; i += 8)
            Wo[(size_t)(by + ty + i) * D + bx + tx] = f2bf(t[tx][ty + i]);
    }
}

// ---------------- 3-phase exclusive scan of (deg[i]-1) -> rowptr[0..n] ----------------

__global__ __launch_bounds__(256) void scan_phase1(
    const int* __restrict__ deg, int* __restrict__ bsum,
    float* __restrict__ dinv, int n) {
    __shared__ int red[256];
    int t = threadIdx.x;
    int i0 = blockIdx.x * 1024 + t * 4;
    int s = 0;
    if (i0 + 3 < n) {
        int4 v = *reinterpret_cast<const int4*>(&deg[i0]);
        s = v.x + v.y + v.z + v.w - 4;
        float4 dv;
        dv.x = rsqrtf((float)v.x); dv.y = rsqrtf((float)v.y);
        dv.z = rsqrtf((float)v.z); dv.w = rsqrtf((float)v.w);
        *reinterpret_cast<float4*>(&dinv[i0]) = dv;
    } else {
        for (int j = i0; j < n && j < i0 + 4; ++j) {
            s += deg[j] - 1;
            dinv[j] = rsqrtf((float)deg[j]);
        }
    }
    red[t] = s;
    __syncthreads();
    for (int off = 128; off > 0; off >>= 1) {
        if (t < off) red[t] += red[t + off];
        __syncthreads();
    }
    if (t == 0) bsum[blockIdx.x] = red[0];
}

__global__ __launch_bounds__(256) void scan_phase2(
    const int* __restrict__ bsum, int* __restrict__ boff,
    int* __restrict__ rowptr, int nblk, int n) {
    __shared__ int sums[256];
    int t = threadIdx.x;
    int v = (t < nblk) ? bsum[t] : 0;
    int orig = v;
    sums[t] = v;
    __syncthreads();
    for (int off = 1; off < 256; off <<= 1) {
        int u = (t >= off) ? sums[t - off] : 0;
        __syncthreads();
        sums[t] += u;
        __syncthreads();
    }
    if (t < nblk) boff[t] = sums[t] - orig;
    if (t == nblk - 1) rowptr[n] = sums[t];
}

__global__ __launch_bounds__(256) void scan_phase3(
    const int* __restrict__ deg, const int* __restrict__ boff,
    int* __restrict__ rowptr, int* __restrict__ cursor, int n) {
    __shared__ int sums[256];
    int t = threadIdx.x;
    int i0 = blockIdx.x * 1024 + t * 4;
    int d0 = 0, d1 = 0, d2 = 0, d3 = 0;
    if (i0 + 3 < n) {
        int4 v = *reinterpret_cast<const int4*>(&deg[i0]);
        d0 = v.x - 1; d1 = v.y - 1; d2 = v.z - 1; d3 = v.w - 1;
    } else {
        if (i0 + 0 < n) d0 = deg[i0 + 0] - 1;
        if (i0 + 1 < n) d1 = deg[i0 + 1] - 1;
        if (i0 + 2 < n) d2 = deg[i0 + 2] - 1;
        if (i0 + 3 < n) d3 = deg[i0 + 3] - 1;
    }
    int ts = d0 + d1 + d2 + d3;
    sums[t] = ts;
    __syncthreads();
    for (int off = 1; off < 256; off <<= 1) {
        int u = (t >= off) ? sums[t - off] : 0;
        __syncthreads();
        sums[t] += u;
        __syncthreads();
    }
    int pre = boff[blockIdx.x] + sums[t] - ts;
    if (i0 + 0 < n) { rowptr[i0 + 0] = pre; cursor[i0 + 0] = pre; } pre += d0;
    if (i0 + 1 < n) { rowptr[i0 + 1] = pre; cursor[i0 + 1] = pre; } pre += d1;
    if (i0 + 2 < n) { rowptr[i0 + 2] = pre; cursor[i0 + 2] = pre; } pre += d2;
    if (i0 + 3 < n) { rowptr[i0 + 3] = pre; cursor[i0 + 3] = pre; }
}

// standalone fill: 4-edge int4 loads, cursor pre-seeded with rowptr
__global__ void fill_kernel(const int* __restrict__ src, const int* __restrict__ dst,
                            int* __restrict__ cursor, int* __restrict__ csr, int e) {
    int i = blockIdx.x * blockDim.x + threadIdx.x;
    int b = i * 4;
    if (b + 3 < e) {
        int4 s4 = *reinterpret_cast<const int4*>(&src[b]);
        int4 d4 = *reinterpret_cast<const int4*>(&dst[b]);
        int p;
        p = atomicAdd(&cursor[d4.x], 1); csr[p] = s4.x;
        p = atomicAdd(&cursor[d4.y], 1); csr[p] = s4.y;
        p = atomicAdd(&cursor[d4.z], 1); csr[p] = s4.z;
        p = atomicAdd(&cursor[d4.w], 1); csr[p] = s4.w;
    } else {
        for (int j = b; j < e; ++j) {
            int d = dst[j];
            int p = atomicAdd(&cursor[d], 1);
            csr[p] = src[j];
        }
    }
}

// ---------------- fused: GEMM1 (f32 A, relu+bias) || hist (4-edge int4) ----------------
__global__ __launch_bounds__(256) void fused_gemm1_hist(
    const float* __restrict__ A, const u16* __restrict__ Bt,
    const float* __restrict__ bias, u16* __restrict__ C, int M, int ng,
    const int* __restrict__ dst, int* __restrict__ deg, int E)
{
    int bid = blockIdx.x;
    if (bid >= ng) {
        int i = (bid - ng) * 256 + threadIdx.x;
        int b = i * 4;
        if (b + 3 < E) {
            int4 v = *reinterpret_cast<const int4*>(&dst[b]);
            atomicAdd(&deg[v.x], 1); atomicAdd(&deg[v.y], 1);
            atomicAdd(&deg[v.z], 1); atomicAdd(&deg[v.w], 1);
        } else {
            for (int j = b; j < E; ++j) atomicAdd(&deg[dst[j]], 1);
        }
        return;
    }
    __shared__ u16 As[64 * 32];
    __shared__ u16 Bs[128 * 32];
    const int tid = threadIdx.x;
    const int lane = tid & 63;
    const int wave = tid >> 6;
    const int wr = wave >> 1, wc = wave & 1;
    const int row0 = (bid >> 1) * 64, col0 = (bid & 1) * 128;
    const int l16 = lane & 15, kg = lane >> 4;

    f32x4 acc[2][4] = {};

    for (int k0 = 0; k0 < D; k0 += 32) {
#pragma unroll
        for (int i = 0; i < 2; ++i) {
            int idx = i * 256 + tid;
            int r = idx >> 2, c = idx & 3;
            int csw = c ^ ((r >> 1) & 3);
            char* ldsbase_b = (char*)Bs + ((i * 256 + (tid & ~63)) << 4);
            gload16(&Bt[(size_t)(col0 + r) * D + k0 + csw * 8], ldsbase_b);
        }
        {
            int r = tid >> 2, c = tid & 3;
            int csw = c ^ ((r >> 1) & 3);
            int grow = row0 + r; if (grow >= M) grow = M - 1;
            const float* gp = &A[(size_t)grow * D + k0 + csw * 8];
            float4 v0 = *reinterpret_cast<const float4*>(gp);
            float4 v1 = *reinterpret_cast<const float4*>(gp + 4);
            uint4 w;
            w.x = cvtpk_bf16(v0.x, v0.y);
            w.y = cvtpk_bf16(v0.z, v0.w);
            w.z = cvtpk_bf16(v1.x, v1.y);
            w.w = cvtpk_bf16(v1.z, v1.w);
            *reinterpret_cast<uint4*>((char*)As + (tid << 4)) = w;
        }
        __syncthreads();
        bf16x8 af[2], bfr[4];
        int ksw = kg ^ ((l16 >> 1) & 3);
#pragma unroll
        for (int m = 0; m < 2; ++m)
            af[m] = *reinterpret_cast<const bf16x8*>(&As[(wr * 32 + m * 16 + l16) * 32 + ksw * 8]);
#pragma unroll
        for (int nn = 0; nn < 4; ++nn)
            bfr[nn] = *reinterpret_cast<const bf16x8*>(&Bs[(wc * 64 + nn * 16 + l16) * 32 + ksw * 8]);
#pragma unroll
        for (int m = 0; m < 2; ++m)
#pragma unroll
            for (int nn = 0; nn < 4; ++nn)
                acc[m][nn] = __builtin_amdgcn_mfma_f32_16x16x32_bf16(
                    af[m], bfr[nn], acc[m][nn], 0, 0, 0);
        __syncthreads();
    }

#pragma unroll
    for (int m = 0; m < 2; ++m) {
#pragma unroll
        for (int nn = 0; nn < 4; ++nn) {
            int gcol = col0 + wc * 64 + nn * 16 + l16;
#pragma unroll
            for (int j = 0; j < 4; ++j) {
                int grow = row0 + wr * 32 + m * 16 + kg * 4 + j;
                if (grow >= M) continue;
                C[(size_t)grow * D + gcol] = f2bf(fmaxf(acc[m][nn][j] + bias[gcol], 0.f));
            }
        }
    }
}

// ---------------- standalone GEMM (bf16 A, *dinv) ----------------
__global__ __launch_bounds__(256) void mfma_gemm(
    const u16* __restrict__ A, const u16* __restrict__ Bt,
    const float* __restrict__ dinv,
    u16* __restrict__ C, int M)
{
    __shared__ u16 As[64 * 32];
    __shared__ u16 Bs[128 * 32];
    const int tid = threadIdx.x;
    const int lane = tid & 63;
    const int wave = tid >> 6;
    const int wr = wave >> 1, wc = wave & 1;
    const int row0 = blockIdx.y * 64, col0 = blockIdx.x * 128;
    const int l16 = lane & 15, kg = lane >> 4;

    f32x4 acc[2][4] = {};

    for (int k0 = 0; k0 < D; k0 += 32) {
        {
            int r = tid >> 2, c = tid & 3;
            int csw = c ^ ((r >> 1) & 3);
            char* ldsbase_a = (char*)As + ((tid & ~63) << 4);
            int grow = row0 + r; if (grow >= M) grow = M - 1;
            gload16(&A[(size_t)grow * D + k0 + csw * 8], ldsbase_a);
        }
#pragma unroll
        for (int i = 0; i < 2; ++i) {
            int idx = i * 256 + tid;
            int r = idx >> 2, c = idx & 3;
            int csw = c ^ ((r >> 1) & 3);
            char* ldsbase_b = (char*)Bs + ((i * 256 + (tid & ~63)) << 4);
            gload16(&Bt[(size_t)(col0 + r) * D + k0 + csw * 8], ldsbase_b);
        }
        __syncthreads();
        bf16x8 af[2], bfr[4];
        int ksw = kg ^ ((l16 >> 1) & 3);
#pragma unroll
        for (int m = 0; m < 2; ++m)
            af[m] = *reinterpret_cast<const bf16x8*>(&As[(wr * 32 + m * 16 + l16) * 32 + ksw * 8]);
#pragma unroll
        for (int nn = 0; nn < 4; ++nn)
            bfr[nn] = *reinterpret_cast<const bf16x8*>(&Bs[(wc * 64 + nn * 16 + l16) * 32 + ksw * 8]);
#pragma unroll
        for (int m = 0; m < 2; ++m)
#pragma unroll
            for (int nn = 0; nn < 4; ++nn)
                acc[m][nn] = __builtin_amdgcn_mfma_f32_16x16x32_bf16(
                    af[m], bfr[nn], acc[m][nn], 0, 0, 0);
        __syncthreads();
    }

#pragma unroll
    for (int m = 0; m < 2; ++m) {
#pragma unroll
        for (int nn = 0; nn < 4; ++nn) {
            int gcol = col0 + wc * 64 + nn * 16 + l16;
#pragma unroll
            for (int j = 0; j < 4; ++j) {
                int grow = row0 + wr * 32 + m * 16 + kg * 4 + j;
                if (grow >= M) continue;
                C[(size_t)grow * D + gcol] = f2bf(acc[m][nn][j] * dinv[grow]);
            }
        }
    }
}

// ---------------- aggregation (r6/r9-verbatim: full-row, forced-MLP bursts) ----------------
__global__ __launch_bounds__(256) void agg_kernel(
    const u16* __restrict__ hn, const int* __restrict__ rowptr,
    const int* __restrict__ csr, const float* __restrict__ dinv,
    const float* __restrict__ bias,
    u16* __restrict__ out_bf, float* __restrict__ out_f32, int n)
{
    int wave = threadIdx.x >> 6;
    int lane = threadIdx.x & 63;
    int node = blockIdx.x * 4 + wave;
    if (node >= n) return;
    int h = lane >> 5;          // half-wave id: edge parity
    int l5 = lane & 31;
    int c8 = l5 * 8;            // column base (8 bf16 = 16B per lane)

    float a[8] = {0.f, 0.f, 0.f, 0.f, 0.f, 0.f, 0.f, 0.f};

#define ACC8(vv) { \
    a[0] += bf2f((u16)(vv)[0]); a[1] += bf2f((u16)(vv)[1]); \
    a[2] += bf2f((u16)(vv)[2]); a[3] += bf2f((u16)(vv)[3]); \
    a[4] += bf2f((u16)(vv)[4]); a[5] += bf2f((u16)(vv)[5]); \
    a[6] += bf2f((u16)(vv)[6]); a[7] += bf2f((u16)(vv)[7]); }
#define ROWP(s) (&hn[(size_t)(s) * D + c8])

    if (h == 0) {
        bf16x8 v = *reinterpret_cast<const bf16x8*>(ROWP(node));
        ACC8(v);
    }

    int e0 = rowptr[node], e1 = rowptr[node + 1];
    for (int base = e0; base < e1; base += 64) {
        int bi = base + lane;
        int idx = (bi < e1) ? csr[bi] : 0;
        int cnt = e1 - base; if (cnt > 64) cnt = 64;
        int it = 0;
        for (; it + 16 <= cnt; it += 16) {
            int s0 = __shfl(idx, it + 0  + h);
            int s1 = __shfl(idx, it + 2  + h);
            int s2 = __shfl(idx, it + 4  + h);
            int s3 = __shfl(idx, it + 6  + h);
            int s4 = __shfl(idx, it + 8  + h);
            int s5 = __shfl(idx, it + 10 + h);
            int s6 = __shfl(idx, it + 12 + h);
            int s7 = __shfl(idx, it + 14 + h);
            bf16x8 v0 = gload_row(ROWP(s0));
            bf16x8 v1 = gload_row(ROWP(s1));
            bf16x8 v2 = gload_row(ROWP(s2));
            bf16x8 v3 = gload_row(ROWP(s3));
            bf16x8 v4 = gload_row(ROWP(s4));
            bf16x8 v5 = gload_row(ROWP(s5));
            bf16x8 v6 = gload_row(ROWP(s6));
            bf16x8 v7 = gload_row(ROWP(s7));
            asm volatile("s_waitcnt vmcnt(0)" ::: "memory");
            __builtin_amdgcn_sched_barrier(0);
            ACC8(v0); ACC8(v1); ACC8(v2); ACC8(v3);
            ACC8(v4); ACC8(v5); ACC8(v6); ACC8(v7);
        }
        for (; it + 8 <= cnt; it += 8) {
            int s0 = __shfl(idx, it + 0 + h);
            int s1 = __shfl(idx, it + 2 + h);
            int s2 = __shfl(idx, it + 4 + h);
            int s3 = __shfl(idx, it + 6 + h);
            bf16x8 v0 = gload_row(ROWP(s0));
            bf16x8 v1 = gload_row(ROWP(s1));
            bf16x8 v2 = gload_row(ROWP(s2));
            bf16x8 v3 = gload_row(ROWP(s3));
            asm volatile("s_waitcnt vmcnt(0)" ::: "memory");
            __builtin_amdgcn_sched_barrier(0);
            ACC8(v0); ACC8(v1); ACC8(v2); ACC8(v3);
        }
        for (; it + 2 <= cnt; it += 2) {
            int s0 = __shfl(idx, it + h);
            bf16x8 v0 = *reinterpret_cast<const bf16x8*>(ROWP(s0));
            ACC8(v0);
        }
        if (it < cnt) {
            int s0 = __shfl(idx, it);
            if (h == 0) {
                bf16x8 v0 = *reinterpret_cast<const bf16x8*>(ROWP(s0));
                ACC8(v0);
            }
        }
    }
#undef ACC8
#undef ROWP

#pragma unroll
    for (int j = 0; j < 8; ++j) a[j] += __shfl(a[j], lane ^ 32);

    if (h == 0) {
        float di = dinv[node];
#pragma unroll
        for (int j = 0; j < 8; ++j) a[j] = fmaxf(a[j] * di + bias[c8 + j], 0.f);
        if (out_bf) {
            bf16x8 o;
#pragma unroll
            for (int j = 0; j < 8; ++j) o[j] = (short)f2bf(a[j]);
            *reinterpret_cast<bf16x8*>(&out_bf[(size_t)node * D + c8]) = o;
        } else {
            float4 o0, o1;
            o0.x = a[0]; o0.y = a[1]; o0.z = a[2]; o0.w = a[3];
            o1.x = a[4]; o1.y = a[5]; o1.z = a[6]; o1.w = a[7];
            *reinterpret_cast<float4*>(&out_f32[(size_t)node * D + c8 + 0]) = o0;
            *reinterpret_cast<float4*>(&out_f32[(size_t)node * D + c8 + 4]) = o1;
        }
    }
}

// ---------------- launch ----------------

extern "C" void kernel_launch(void* const* d_in, const int* in_sizes, int n_in,
                              void* d_out, int out_size, void* d_ws, size_t ws_size,
                              hipStream_t stream) {
    const float* input  = (const float*)d_in[0];
    const int*   edge   = (const int*)d_in[1];
    const float* weight = (const float*)d_in[2];
    const float* bias   = (const float*)d_in[3];
    const float* conv_w = (const float*)d_in[4];
    const float* conv_b = (const float*)d_in[5];
    float* out = (float*)d_out;

    const int n = in_sizes[0] / D;     // 50000
    const int E = in_sizes[1] / 2;     // 800000
    const int* src = edge;
    const int* dst = edge + E;

    char* ws = (char*)d_ws;
    size_t off = 0;
    auto alloc = [&](size_t bytes) -> void* {
        void* p = ws + off;
        off = (off + bytes + 255) & ~(size_t)255;
        return p;
    };
    u16*   bufA   = (u16*)alloc((size_t)n * D * sizeof(u16));   // x1 / x2
    u16*   bufB   = (u16*)alloc((size_t)n * D * sizeof(u16));   // hn / hn2
    u16*   Wt     = (u16*)alloc((size_t)3 * D * D * sizeof(u16));
    int*   deg    = (int*)alloc((size_t)n * sizeof(int));
    int*   cursor = (int*)alloc((size_t)n * sizeof(int));
    float* dinv   = (float*)alloc((size_t)n * sizeof(float));
    int*   rowptr = (int*)alloc((size_t)(n + 1) * sizeof(int));
    int*   csr    = (int*)alloc((size_t)E * sizeof(int));
    int    nscan  = (n + 1023) / 1024;
    int*   bsum   = (int*)alloc((size_t)nscan * sizeof(int));
    int*   boff   = (int*)alloc((size_t)nscan * sizeof(int));

    int nb  = (n + 255) / 256;           // init blocks (196)
    int eb4 = (E / 4 + 255) / 256;       // 4 edge/thread blocks (782)
    int ng  = 2 * ((n + 63) / 64);       // gemm blocks (1564)

    // init || transpose x3
    fused_init_tr<<<nb + 192, 256, 0, stream>>>(deg, n, nb, weight, conv_w, Wt);
    // GEMM1 (x1 = relu(input@W + b) -> bufA) || hist (4-edge int4)
    fused_gemm1_hist<<<ng + eb4, 256, 0, stream>>>(input, Wt, bias, bufA, n, ng, dst, deg, E);
    // scan chain (rowptr, cursor pre-seed, dinv)
    scan_phase1<<<nscan, 256, 0, stream>>>(deg, bsum, dinv, n);
    scan_phase2<<<1, 256, 0, stream>>>(bsum, boff, rowptr, nscan, n);
    scan_phase3<<<nscan, 256, 0, stream>>>(deg, boff, rowptr, cursor, n);
    // fill (standalone, 4-edge int4, pre-seeded cursor)
    fill_kernel<<<eb4, 256, 0, stream>>>(src, dst, cursor, csr, E);

    dim3 ggrid(D / 128, (n + 63) / 64);
    dim3 agrid((n + 3) / 4);
    // hn = (x1 @ W0) * dinv[row]        -> bufB
    mfma_gemm<<<ggrid, 256, 0, stream>>>(bufA, Wt + D * D, dinv, bufB, n);
    // x2 = relu(dinv * agg(hn) + b0)    -> bufA
    agg_kernel<<<agrid, 256, 0, stream>>>(bufB, rowptr, csr, dinv, conv_b, bufA, nullptr, n);
    // hn2 = (x2 @ W1) * dinv[row]       -> bufB
    mfma_gemm<<<ggrid, 256, 0, stream>>>(bufA, Wt + 2 * D * D, dinv, bufB, n);
    // out = relu(dinv * agg(hn2) + b1)  -> out (f32)
    agg_kernel<<<agrid, 256, 0, stream>>>(bufB, rowptr, csr, dinv, conv_b + D, nullptr, out, n);
}